// Round 3
// baseline (2330.474 us; speedup 1.0000x reference)
//
#include <hip/hip_runtime.h>
#include <cstdint>
#include <cstddef>

#define BH_N    32
#define NK      4096
#define DIM     64
#define KKEEP   409
#define QSCALE  0.125f

#define MROWS   64
#define THREADS 512
#define CHUNK   128
#define NCHUNK  (NK / CHUNK)
// Histogram over [0.4, 2.4], 192 bins of width 1/96. Candidate window =
// 1/96 + 4*EPS = 0.0304 score units -> ~22 candidates/row typical, ~31 for
// low-|q| rows (sigma_r ~ 0.7); CCAP=64 overflow is >4 sigma away.
#define HIST_LO 0.40f
#define HIST_INV 96.0f
#define HIST_BINS 192
#define EPS     0.005f
// Lower candidate edge is a constant offset below thU: thL = thU - TH_GAP.
// (Replaces the thL_r[4] register array; window size identical to +-ulps.)
#define TH_GAP  (1.0f / HIST_INV + 4.0f * EPS)
#define CCAP    64

typedef _Float16 f16x8 __attribute__((ext_vector_type(8)));
typedef float f32x4 __attribute__((ext_vector_type(4)));

// ---- LDS layout (bytes). Regions reused across phases. ----
// hist (24576 B) overlays VT + PBUF (both Phase-B-only); consumed before
// Phase B's first V/P write with a barrier between. Footprint 50944 B ->
// LDS permits 3 blocks/CU.
//
// Occupancy history (this is the binding constraint, tracked carefully):
//   R0 (512,4), 63 KB LDS: 2 blk/CU, 1475 us.
//   R1 (512,6), 50 KB LDS: 3 blk/CU (63% occ) BUT arch VGPR squeezed to 40
//      -> scratch spills in chunk loops (FETCH 62MB->2.7GB), 2427 us.
//   R2 (512,4), 50 KB LDS: no spills, but compiler used the full 128-reg
//      budget (64 arch + acc) -> only 2 blk/CU (41% occ), 1519 us.
// This round: (512,6) again, WITH source-level pressure trims (thL_r gone,
// incremental staging converts) so total arch+acc fits 512/6 = 85 without
// spilling. Spill tripwire: FETCH_SIZE >> 70 MB.
#define OFF_KC    0        // 16384 : fp16 K chunk [128 key][64 d], swizzled; reused as candS f32[64][64]
#define OFF_VT    16384    // 16384 : fp16 V chunk transposed [64 d][128 key], swizzled; reused as outacc f32[64][64]; Phase A: hist lo
#define OFF_PBUF  32768    // 8192  : per-wave P tile fp16 [16 m][32 k], swizzled (1024 B/wave) [Phase B only]; Phase A: hist hi
#define OFF_HIST  16384    // 24576 : u32 (u16-pair) hist [64 row][96]  (= VT+PBUF regions, Phase A only)
#define OFF_CANDJ 40960    // 8192  : u16 [64 row][64] [Phase B + resolution]
#define OFF_MISC  49152    // rmaxI i32[64], thU f32[64], (unused f32[64]), mval f32[64], candCnt u32[64], c1cnt u32[64], zrow f32[64]
#define SMEM_SZ   (49152 + 7*256)

__device__ __forceinline__ int kc_off(int key, int g) {   // halfs; granule g = d/8
  return key * 64 + ((g ^ (key & 7)) << 3);
}
// V-transpose swizzle folds in BOTH d&15 and d>>4 (verified R1: staging
// write conflicts 9.75e7 -> 4.7e7; perf-neutral but kept, it is free).
__device__ __forceinline__ int vt_off(int d, int kb) {    // halfs; granule kb = key/8
  return d * 128 + ((kb ^ (d & 15) ^ (d >> 4)) << 3);
}
__device__ __forceinline__ int pb_off(int m, int g) {     // halfs; granule g = k/8
  return m * 32 + ((g ^ (m & 3)) << 3);
}

__global__ __launch_bounds__(THREADS, 6) void fused_topk_attn(
    const float* __restrict__ q, const float* __restrict__ k,
    const float* __restrict__ v, float* __restrict__ out) {
  __shared__ __align__(16) unsigned char smem[SMEM_SZ];
  _Float16* kc   = (_Float16*)(smem + OFF_KC);
  _Float16* vt   = (_Float16*)(smem + OFF_VT);
  unsigned int* hist = (unsigned int*)(smem + OFF_HIST);
  _Float16* pbuf = (_Float16*)(smem + OFF_PBUF);
  unsigned short* candJ = (unsigned short*)(smem + OFF_CANDJ);
  int*   rmaxI  = (int*)(smem + OFF_MISC);
  float* thU    = (float*)(smem + OFF_MISC + 256);
  float* mval   = (float*)(smem + OFF_MISC + 768);
  unsigned int* candCnt = (unsigned int*)(smem + OFF_MISC + 1024);
  unsigned int* c1cnt   = (unsigned int*)(smem + OFF_MISC + 1280);
  float* zrow   = (float*)(smem + OFF_MISC + 1536);
  float* candS  = (float*)(smem + OFF_KC);     // reuse Kc after chunks
  float* outacc = (float*)(smem + OFF_VT);     // reuse Vt after chunks

  const int tid  = threadIdx.x;
  const int wave = tid >> 6, lane = tid & 63;
  const int am = lane & 15, aq = lane >> 4;    // mfma lane coords
  const int mt = wave & 3, hh = wave >> 2;     // m-tile, n-half

  // Grid mapping: same-bh blocks land on the same XCD (L2 locality).
  const int bid = blockIdx.x;
  const int xcd = bid & 7, idx = bid >> 3;
  const int bh  = xcd + 8 * (idx >> 6);
  const int mrow0 = (idx & 63) * MROWS;

  const float* qb = q + (size_t)bh * NK * DIM;
  const float* kb_ = k + (size_t)bh * NK * DIM;
  const float* vb = v + (size_t)bh * NK * DIM;
  float* ob = out + (size_t)bh * NK * DIM;

  // ---- init LDS ----
  for (int i = tid; i < 64 * (HIST_BINS / 2); i += THREADS) hist[i] = 0u;
  if (tid < 64) rmaxI[tid] = 0;
  __syncthreads();

  // ---- A-fragments (q/8 in fp16), persist in registers ----
  const int rbase = mrow0 + mt * 16;
  f16x8 A0, A1;
  {
    const float* qrow = qb + (size_t)(rbase + am) * DIM + aq * 8;
#pragma unroll
    for (int j = 0; j < 8; ++j) A0[j] = (_Float16)(qrow[j] * QSCALE);
#pragma unroll
    for (int j = 0; j < 8; ++j) A1[j] = (_Float16)(qrow[32 + j] * QSCALE);
  }

  // ================= PHASE A: screen GEMM -> max + histogram =================
  float rmax[4] = {-1e30f, -1e30f, -1e30f, -1e30f};
#pragma unroll 1
  for (int ch = 0; ch < NCHUNK; ++ch) {
    const int key0 = ch * CHUNK;
    {  // stage K chunk -> fp16 LDS (coalesced 32 KB read, incremental convert)
      const int key = tid >> 2, seg = tid & 3;
      const float4* src = (const float4*)(kb_ + (size_t)(key0 + key) * DIM) + seg * 4;
      float4 a0 = src[0], a1 = src[1], a2 = src[2], a3 = src[3];
      f16x8 h0;
      h0[0]=(_Float16)a0.x; h0[1]=(_Float16)a0.y; h0[2]=(_Float16)a0.z; h0[3]=(_Float16)a0.w;
      h0[4]=(_Float16)a1.x; h0[5]=(_Float16)a1.y; h0[6]=(_Float16)a1.z; h0[7]=(_Float16)a1.w;
      *(f16x8*)(kc + kc_off(key, seg * 2)) = h0;
      f16x8 h1;
      h1[0]=(_Float16)a2.x; h1[1]=(_Float16)a2.y; h1[2]=(_Float16)a2.z; h1[3]=(_Float16)a2.w;
      h1[4]=(_Float16)a3.x; h1[5]=(_Float16)a3.y; h1[6]=(_Float16)a3.z; h1[7]=(_Float16)a3.w;
      *(f16x8*)(kc + kc_off(key, seg * 2 + 1)) = h1;
    }
    __syncthreads();
#pragma unroll
    for (int tl = 0; tl < 4; ++tl) {
      const int keyloc = hh * 64 + tl * 16 + am;
      f16x8 b0 = *(const f16x8*)(kc + kc_off(keyloc, aq));
      f16x8 b1 = *(const f16x8*)(kc + kc_off(keyloc, aq + 4));
      f32x4 acc = {0.f, 0.f, 0.f, 0.f};
      acc = __builtin_amdgcn_mfma_f32_16x16x32_f16(A0, b0, acc, 0, 0, 0);
      acc = __builtin_amdgcn_mfma_f32_16x16x32_f16(A1, b1, acc, 0, 0, 0);
#pragma unroll
      for (int r = 0; r < 4; ++r) {
        float s = acc[r];
        rmax[r] = fmaxf(rmax[r], s);
        if (s >= HIST_LO) {
          int bin = (int)((s - HIST_LO) * HIST_INV);
          bin = bin > (HIST_BINS - 1) ? (HIST_BINS - 1) : bin;
          atomicAdd(hist + (mt * 16 + aq * 4 + r) * (HIST_BINS / 2) + (bin >> 1),
                    (bin & 1) ? 65536u : 1u);
        }
      }
    }
    __syncthreads();
  }
  // row max -> LDS
#pragma unroll
  for (int off = 1; off < 16; off <<= 1)
#pragma unroll
    for (int r = 0; r < 4; ++r) rmax[r] = fmaxf(rmax[r], __shfl_xor(rmax[r], off));
  if (am == 0) {
#pragma unroll
    for (int r = 0; r < 4; ++r)
      atomicMax(rmaxI + mt * 16 + aq * 4 + r, __float_as_int(rmax[r]));
  }
  __syncthreads();

  // ---- per-row threshold bracket from histogram ----
  if (tid < 64) {
    const unsigned int* hrow = hist + tid * (HIST_BINS / 2);
    unsigned int cum = 0; int bsel = 0;
    for (int b = HIST_BINS - 1; b >= 0; --b) {
      unsigned int pr = hrow[b >> 1];
      cum += (b & 1) ? (pr >> 16) : (pr & 0xffffu);
      if (cum >= KKEEP) { bsel = b; break; }
    }
    float lowerE = HIST_LO + (float)bsel * (1.0f / HIST_INV);
    float upperE = lowerE + (1.0f / HIST_INV);
    thU[tid] = upperE + 2.0f * EPS;
    mval[tid] = __int_as_float(rmaxI[tid]);
    candCnt[tid] = 0u; c1cnt[tid] = 0u; zrow[tid] = 0.f;
  }
  __syncthreads();

  float thU_r[4], m_r[4];
#pragma unroll
  for (int r = 0; r < 4; ++r) {
    int rb = mt * 16 + aq * 4 + r;
    thU_r[r] = thU[rb]; m_r[r] = mval[rb];
  }

  // ================= PHASE B: re-screen + classify + fused PV-MFMA =================
  f32x4 pv[4];
#pragma unroll
  for (int d = 0; d < 4; ++d) pv[d] = (f32x4){0.f, 0.f, 0.f, 0.f};
  float zs[4] = {0.f, 0.f, 0.f, 0.f};
  int c1l[4] = {0, 0, 0, 0};
  _Float16* Pw = pbuf + wave * 512;

#pragma unroll 1
  for (int ch = 0; ch < NCHUNK; ++ch) {
    const int key0 = ch * CHUNK;
    {  // stage K chunk (identical conversion -> bitwise-identical scores)
      const int key = tid >> 2, seg = tid & 3;
      const float4* src = (const float4*)(kb_ + (size_t)(key0 + key) * DIM) + seg * 4;
      float4 a0 = src[0], a1 = src[1], a2 = src[2], a3 = src[3];
      f16x8 h0;
      h0[0]=(_Float16)a0.x; h0[1]=(_Float16)a0.y; h0[2]=(_Float16)a0.z; h0[3]=(_Float16)a0.w;
      h0[4]=(_Float16)a1.x; h0[5]=(_Float16)a1.y; h0[6]=(_Float16)a1.z; h0[7]=(_Float16)a1.w;
      *(f16x8*)(kc + kc_off(key, seg * 2)) = h0;
      f16x8 h1;
      h1[0]=(_Float16)a2.x; h1[1]=(_Float16)a2.y; h1[2]=(_Float16)a2.z; h1[3]=(_Float16)a2.w;
      h1[4]=(_Float16)a3.x; h1[5]=(_Float16)a3.y; h1[6]=(_Float16)a3.z; h1[7]=(_Float16)a3.w;
      *(f16x8*)(kc + kc_off(key, seg * 2 + 1)) = h1;
    }
    {  // stage V chunk transposed -> fp16 LDS (direct converts, no temp array)
      const int key = tid >> 2, seg = tid & 3;
      const float4* src = (const float4*)(vb + (size_t)(key0 + key) * DIM) + seg * 4;
      float4 a0 = src[0], a1 = src[1], a2 = src[2], a3 = src[3];
      const int kbg = key >> 3, kl = key & 7;
      const int d0 = seg * 16;
      vt[vt_off(d0 +  0, kbg) + kl] = (_Float16)a0.x;
      vt[vt_off(d0 +  1, kbg) + kl] = (_Float16)a0.y;
      vt[vt_off(d0 +  2, kbg) + kl] = (_Float16)a0.z;
      vt[vt_off(d0 +  3, kbg) + kl] = (_Float16)a0.w;
      vt[vt_off(d0 +  4, kbg) + kl] = (_Float16)a1.x;
      vt[vt_off(d0 +  5, kbg) + kl] = (_Float16)a1.y;
      vt[vt_off(d0 +  6, kbg) + kl] = (_Float16)a1.z;
      vt[vt_off(d0 +  7, kbg) + kl] = (_Float16)a1.w;
      vt[vt_off(d0 +  8, kbg) + kl] = (_Float16)a2.x;
      vt[vt_off(d0 +  9, kbg) + kl] = (_Float16)a2.y;
      vt[vt_off(d0 + 10, kbg) + kl] = (_Float16)a2.z;
      vt[vt_off(d0 + 11, kbg) + kl] = (_Float16)a2.w;
      vt[vt_off(d0 + 12, kbg) + kl] = (_Float16)a3.x;
      vt[vt_off(d0 + 13, kbg) + kl] = (_Float16)a3.y;
      vt[vt_off(d0 + 14, kbg) + kl] = (_Float16)a3.z;
      vt[vt_off(d0 + 15, kbg) + kl] = (_Float16)a3.w;
    }
    __syncthreads();

#pragma unroll
    for (int grp = 0; grp < 2; ++grp) {
      // zero my P tile (each lane zeroes exactly its A-frag granule)
      *(f16x8*)(Pw + pb_off(am, aq)) = (f16x8){(_Float16)0,(_Float16)0,(_Float16)0,(_Float16)0,
                                               (_Float16)0,(_Float16)0,(_Float16)0,(_Float16)0};
#pragma unroll
      for (int t2 = 0; t2 < 2; ++t2) {
        const int keyloc = hh * 64 + grp * 32 + t2 * 16 + am;
        f16x8 b0 = *(const f16x8*)(kc + kc_off(keyloc, aq));
        f16x8 b1 = *(const f16x8*)(kc + kc_off(keyloc, aq + 4));
        f32x4 acc = {0.f, 0.f, 0.f, 0.f};
        acc = __builtin_amdgcn_mfma_f32_16x16x32_f16(A0, b0, acc, 0, 0, 0);
        acc = __builtin_amdgcn_mfma_f32_16x16x32_f16(A1, b1, acc, 0, 0, 0);
#pragma unroll
        for (int r = 0; r < 4; ++r) {
          float s = acc[r];
          if (s > thU_r[r]) {
            _Float16 wh = (_Float16)__expf(s - m_r[r]);
            zs[r] += (float)wh;          // z matches the fp16 weight used in PV
            c1l[r] += 1;
            const int m = aq * 4 + r, kl = t2 * 16 + am;
            Pw[m * 32 + (((kl >> 3) ^ (m & 3)) << 3) + (kl & 7)] = wh;
          } else if (s >= thU_r[r] - TH_GAP) {
            int rb = mt * 16 + aq * 4 + r;
            unsigned int p = atomicAdd(candCnt + rb, 1u);
            if (p < CCAP) candJ[rb * CCAP + p] = (unsigned short)(key0 + keyloc);
          }
        }
      }
      // PV mfma: out[16 m][64 d] += P[16 m][32 key] x V[32 key][64 d]
      f16x8 pA = *(const f16x8*)(Pw + pb_off(am, aq));
#pragma unroll
      for (int dt = 0; dt < 4; ++dt) {
        f16x8 vB = *(const f16x8*)(vt + vt_off(dt * 16 + am, hh * 8 + grp * 4 + aq));
        pv[dt] = __builtin_amdgcn_mfma_f32_16x16x32_f16(pA, vB, pv[dt], 0, 0, 0);
      }
    }
    __syncthreads();
  }

  // ---- dump PV accumulators + Z/C1 reductions ----
  for (int i = tid; i < MROWS * DIM; i += THREADS) outacc[i] = 0.f;
  __syncthreads();
#pragma unroll
  for (int dt = 0; dt < 4; ++dt)
#pragma unroll
    for (int r = 0; r < 4; ++r)
      atomicAdd(outacc + (mt * 16 + aq * 4 + r) * 64 + dt * 16 + am, pv[dt][r]);
#pragma unroll
  for (int off = 1; off < 16; off <<= 1)
#pragma unroll
    for (int r = 0; r < 4; ++r) {
      zs[r] += __shfl_xor(zs[r], off);
      c1l[r] += __shfl_xor(c1l[r], off);
    }
  if (am == 0) {
#pragma unroll
    for (int r = 0; r < 4; ++r) {
      int rb = mt * 16 + aq * 4 + r;
      atomicAdd(zrow + rb, zs[r]);
      atomicAdd(c1cnt + rb, (unsigned int)c1l[r]);
    }
  }
  __syncthreads();

  // ---- candidate resolution: exact fp32 dots + exact top-(409-C1) ----
  for (int i = 0; i < 8; ++i) {
    const int rb = wave * 8 + i;
    const int nc = min((int)candCnt[rb], CCAP);
    int need = KKEEP - (int)c1cnt[rb];
    need = need < 0 ? 0 : (need > nc ? nc : need);   // DEFENSIVE: never exceed nc
    const float mv = mval[rb];
    const float qv = qb[(size_t)(mrow0 + rb) * DIM + lane] * QSCALE;
    for (int c = 0; c < nc; ++c) {
      int col = candJ[rb * CCAP + c] & (NK - 1);
      float p = qv * kb_[(size_t)col * DIM + lane];
#pragma unroll
      for (int off = 1; off < 64; off <<= 1) p += __shfl_xor(p, off);
      if (lane == 0) candS[rb * CCAP + c] = p;
    }
    float sc = (lane < nc) ? candS[rb * CCAP + lane] : -1e30f;
    int bi = __float_as_int(sc);
    unsigned int u = (bi >= 0) ? ((unsigned int)bi | 0x80000000u) : ~(unsigned int)bi;
    unsigned int T = 0;
    for (int bit = 31; bit >= 0; --bit) {
      unsigned int trial = T | (1u << bit);
      unsigned long long mk = __ballot((lane < nc) && (u >= trial));
      if (__popcll(mk) >= need) T = trial;
    }
    bool sel = (lane < nc) && (u > T);
    int need2 = need - __popcll(__ballot(sel));
    int col_l = (lane < nc) ? (int)(candJ[rb * CCAP + lane] & (NK - 1)) : 0x7fffffff;
    int guard = 0;
    while (need2 > 0 && guard < CCAP) {  // np tie-break: lowest index first
      int cnd = (lane < nc && u == T && !sel) ? col_l : 0x7fffffff;
#pragma unroll
      for (int off = 1; off < 64; off <<= 1) cnd = min(cnd, __shfl_xor(cnd, off));
      if (lane < nc && u == T && col_l == cnd) sel = true;
      --need2; ++guard;
    }
    unsigned long long selm = __ballot(sel);
    float zadd = 0.f;
    float oa = outacc[rb * 64 + lane];
    while (selm) {
      int c = __ffsll((unsigned long long)selm) - 1;
      selm &= selm - 1;
      float w = __expf(candS[rb * CCAP + c] - mv);
      int col = candJ[rb * CCAP + c] & (NK - 1);
      oa += w * vb[(size_t)col * DIM + lane];
      zadd += w;
    }
    outacc[rb * 64 + lane] = oa;
    if (lane == 0) zrow[rb] += zadd;
  }
  __syncthreads();

  // ---- normalize + write ----
  for (int i = tid; i < MROWS * DIM; i += THREADS) {
    int rb = i >> 6;
    ob[(size_t)(mrow0 + rb) * DIM + (i & 63)] = outacc[i] / zrow[rb];
  }
}

// ---------------------------------------------------------------------------
extern "C" void kernel_launch(void* const* d_in, const int* in_sizes, int n_in,
                              void* d_out, int out_size, void* d_ws,
                              size_t ws_size, hipStream_t stream) {
  const float* q = (const float*)d_in[0];
  const float* k = (const float*)d_in[1];
  const float* v = (const float*)d_in[2];
  float* out = (float*)d_out;
  const int nblocks = (BH_N * NK) / MROWS;  // 2048
  fused_topk_attn<<<nblocks, THREADS, 0, stream>>>(q, k, v, out);
}

// Round 4
// 1170.133 us; speedup vs baseline: 1.9916x; 1.9916x over previous
//
#include <hip/hip_runtime.h>
#include <cstdint>
#include <cstddef>

#define BH_N    32
#define NK      4096
#define DIM     64
#define KKEEP   409
#define QSCALE  0.125f

#define MROWS   64
#define THREADS 512
#define CHUNK   128
#define NCHUNK  (NK / CHUNK)
// Histogram over [0.6, 2.6], 192 bins of width 1/96. Per-row threshold
// (409th of 4096) ~= 1.27*|q|/8; falling below 0.6 needs |q|<4.3,
// P(chi2_64 < 18.6) ~ 7e-9 per row -> safe. LO=0.6 (was 0.4) cuts the
// Phase-A hist-atomic rate from P(s>0.4)=0.35 to P(s>0.6)=0.27.
#define HIST_LO 0.60f
#define HIST_INV 96.0f
#define HIST_BINS 192
#define EPS     0.005f
// Lower candidate edge is a constant offset below thU: thL = thU - TH_GAP.
#define TH_GAP  (1.0f / HIST_INV + 4.0f * EPS)
#define CCAP    64

typedef _Float16 f16x8 __attribute__((ext_vector_type(8)));
typedef float f32x4 __attribute__((ext_vector_type(4)));

// ---- LDS layout (bytes). Regions reused across phases. ----
// hist (24576 B) overlays VT + PBUF (both Phase-B-only). Footprint 50944 B.
//
// Occupancy history (binding constraint = TOTAL regs, arch+acc, unified file):
//   R0 (512,4), 63 KB LDS: 2 blk/CU, 1475 us.
//   R1 (512,6): arch VGPR forced to 40 -> scratch spills (FETCH 62MB->2.7GB), 2427 us.
//   R2 (512,4), 50 KB LDS: 64 VGPR, no spills, 2 blk/CU, 1519 us.
//   R3 (512,6) + source trims: STILL spills (FETCH 2.4GB), 2330 us.
// CONCLUSION: 3 blk/CU needs total<=85 regs; kernel needs ~128. (512,4) is
// final. Round 4 attacks the serial candidate-resolution tail instead
// (dependent load->shuffle chains, ~22 serial iterations/row, 8 rows/wave).
#define OFF_KC    0        // 16384 : fp16 K chunk [128 key][64 d], swizzled; reused as candS f32[64][64]
#define OFF_VT    16384    // 16384 : fp16 V chunk transposed [64 d][128 key], swizzled; reused as outacc f32[64][64]; Phase A: hist lo
#define OFF_PBUF  32768    // 8192  : per-wave P tile fp16 [16 m][32 k] (1024 B/wave) [Phase B]; Phase A: hist hi; tail: per-wave scratch
#define OFF_HIST  16384    // 24576 : u32 (u16-pair) hist [64 row][96]  (= VT+PBUF regions, Phase A only)
#define OFF_CANDJ 40960    // 8192  : u16 [64 row][64] [Phase B + resolution]
#define OFF_MISC  49152    // rmaxI i32[64], thU f32[64], (gap), mval f32[64], candCnt u32[64], c1cnt u32[64], zrow f32[64]
#define SMEM_SZ   (49152 + 7*256)

__device__ __forceinline__ int kc_off(int key, int g) {   // halfs; granule g = d/8
  return key * 64 + ((g ^ (key & 7)) << 3);
}
// V-transpose swizzle folds in BOTH d&15 and d>>4 (verified R1: staging
// write conflicts 9.75e7 -> 4.7e7; perf-neutral but free).
__device__ __forceinline__ int vt_off(int d, int kb) {    // halfs; granule kb = key/8
  return d * 128 + ((kb ^ (d & 15) ^ (d >> 4)) << 3);
}
__device__ __forceinline__ int pb_off(int m, int g) {     // halfs; granule g = k/8
  return m * 32 + ((g ^ (m & 3)) << 3);
}

__global__ __launch_bounds__(THREADS, 4) void fused_topk_attn(
    const float* __restrict__ q, const float* __restrict__ k,
    const float* __restrict__ v, float* __restrict__ out) {
  __shared__ __align__(16) unsigned char smem[SMEM_SZ];
  _Float16* kc   = (_Float16*)(smem + OFF_KC);
  _Float16* vt   = (_Float16*)(smem + OFF_VT);
  unsigned int* hist = (unsigned int*)(smem + OFF_HIST);
  _Float16* pbuf = (_Float16*)(smem + OFF_PBUF);
  unsigned short* candJ = (unsigned short*)(smem + OFF_CANDJ);
  int*   rmaxI  = (int*)(smem + OFF_MISC);
  float* thU    = (float*)(smem + OFF_MISC + 256);
  float* mval   = (float*)(smem + OFF_MISC + 768);
  unsigned int* candCnt = (unsigned int*)(smem + OFF_MISC + 1024);
  unsigned int* c1cnt   = (unsigned int*)(smem + OFF_MISC + 1280);
  float* zrow   = (float*)(smem + OFF_MISC + 1536);
  float* candS  = (float*)(smem + OFF_KC);     // reuse Kc after chunks
  float* outacc = (float*)(smem + OFF_VT);     // reuse Vt after chunks

  const int tid  = threadIdx.x;
  const int wave = tid >> 6, lane = tid & 63;
  const int am = lane & 15, aq = lane >> 4;    // mfma lane coords
  const int mt = wave & 3, hh = wave >> 2;     // m-tile, n-half

  // Grid mapping: same-bh blocks land on the same XCD (L2 locality).
  const int bid = blockIdx.x;
  const int xcd = bid & 7, idx = bid >> 3;
  const int bh  = xcd + 8 * (idx >> 6);
  const int mrow0 = (idx & 63) * MROWS;

  const float* qb = q + (size_t)bh * NK * DIM;
  const float* kb_ = k + (size_t)bh * NK * DIM;
  const float* vb = v + (size_t)bh * NK * DIM;
  float* ob = out + (size_t)bh * NK * DIM;

  // ---- init LDS ----
  for (int i = tid; i < 64 * (HIST_BINS / 2); i += THREADS) hist[i] = 0u;
  if (tid < 64) rmaxI[tid] = 0;
  __syncthreads();

  // ---- A-fragments (q/8 in fp16), persist in registers ----
  const int rbase = mrow0 + mt * 16;
  f16x8 A0, A1;
  {
    const float* qrow = qb + (size_t)(rbase + am) * DIM + aq * 8;
#pragma unroll
    for (int j = 0; j < 8; ++j) A0[j] = (_Float16)(qrow[j] * QSCALE);
#pragma unroll
    for (int j = 0; j < 8; ++j) A1[j] = (_Float16)(qrow[32 + j] * QSCALE);
  }

  // ================= PHASE A: screen GEMM -> max + histogram =================
  float rmax[4] = {-1e30f, -1e30f, -1e30f, -1e30f};
#pragma unroll 1
  for (int ch = 0; ch < NCHUNK; ++ch) {
    const int key0 = ch * CHUNK;
    {  // stage K chunk -> fp16 LDS (coalesced 32 KB read)
      const int key = tid >> 2, seg = tid & 3;
      const float4* src = (const float4*)(kb_ + (size_t)(key0 + key) * DIM) + seg * 4;
      float4 a0 = src[0], a1 = src[1], a2 = src[2], a3 = src[3];
      f16x8 h0;
      h0[0]=(_Float16)a0.x; h0[1]=(_Float16)a0.y; h0[2]=(_Float16)a0.z; h0[3]=(_Float16)a0.w;
      h0[4]=(_Float16)a1.x; h0[5]=(_Float16)a1.y; h0[6]=(_Float16)a1.z; h0[7]=(_Float16)a1.w;
      *(f16x8*)(kc + kc_off(key, seg * 2)) = h0;
      f16x8 h1;
      h1[0]=(_Float16)a2.x; h1[1]=(_Float16)a2.y; h1[2]=(_Float16)a2.z; h1[3]=(_Float16)a2.w;
      h1[4]=(_Float16)a3.x; h1[5]=(_Float16)a3.y; h1[6]=(_Float16)a3.z; h1[7]=(_Float16)a3.w;
      *(f16x8*)(kc + kc_off(key, seg * 2 + 1)) = h1;
    }
    __syncthreads();
#pragma unroll
    for (int tl = 0; tl < 4; ++tl) {
      const int keyloc = hh * 64 + tl * 16 + am;
      f16x8 b0 = *(const f16x8*)(kc + kc_off(keyloc, aq));
      f16x8 b1 = *(const f16x8*)(kc + kc_off(keyloc, aq + 4));
      f32x4 acc = {0.f, 0.f, 0.f, 0.f};
      acc = __builtin_amdgcn_mfma_f32_16x16x32_f16(A0, b0, acc, 0, 0, 0);
      acc = __builtin_amdgcn_mfma_f32_16x16x32_f16(A1, b1, acc, 0, 0, 0);
#pragma unroll
      for (int r = 0; r < 4; ++r) {
        float s = acc[r];
        rmax[r] = fmaxf(rmax[r], s);
        if (s >= HIST_LO) {
          int bin = (int)((s - HIST_LO) * HIST_INV);
          bin = bin > (HIST_BINS - 1) ? (HIST_BINS - 1) : bin;
          atomicAdd(hist + (mt * 16 + aq * 4 + r) * (HIST_BINS / 2) + (bin >> 1),
                    (bin & 1) ? 65536u : 1u);
        }
      }
    }
    __syncthreads();
  }
  // row max -> LDS
#pragma unroll
  for (int off = 1; off < 16; off <<= 1)
#pragma unroll
    for (int r = 0; r < 4; ++r) rmax[r] = fmaxf(rmax[r], __shfl_xor(rmax[r], off));
  if (am == 0) {
#pragma unroll
    for (int r = 0; r < 4; ++r)
      atomicMax(rmaxI + mt * 16 + aq * 4 + r, __float_as_int(rmax[r]));
  }
  __syncthreads();

  // ---- per-row threshold bracket from histogram ----
  if (tid < 64) {
    const unsigned int* hrow = hist + tid * (HIST_BINS / 2);
    unsigned int cum = 0; int bsel = 0;
    for (int b = HIST_BINS - 1; b >= 0; --b) {
      unsigned int pr = hrow[b >> 1];
      cum += (b & 1) ? (pr >> 16) : (pr & 0xffffu);
      if (cum >= KKEEP) { bsel = b; break; }
    }
    float lowerE = HIST_LO + (float)bsel * (1.0f / HIST_INV);
    float upperE = lowerE + (1.0f / HIST_INV);
    thU[tid] = upperE + 2.0f * EPS;
    mval[tid] = __int_as_float(rmaxI[tid]);
    candCnt[tid] = 0u; c1cnt[tid] = 0u; zrow[tid] = 0.f;
  }
  __syncthreads();

  float thU_r[4], m_r[4];
#pragma unroll
  for (int r = 0; r < 4; ++r) {
    int rb = mt * 16 + aq * 4 + r;
    thU_r[r] = thU[rb]; m_r[r] = mval[rb];
  }

  // ================= PHASE B: re-screen + classify + fused PV-MFMA =================
  f32x4 pv[4];
#pragma unroll
  for (int d = 0; d < 4; ++d) pv[d] = (f32x4){0.f, 0.f, 0.f, 0.f};
  float zs[4] = {0.f, 0.f, 0.f, 0.f};
  int c1l[4] = {0, 0, 0, 0};
  _Float16* Pw = pbuf + wave * 512;

#pragma unroll 1
  for (int ch = 0; ch < NCHUNK; ++ch) {
    const int key0 = ch * CHUNK;
    {  // stage K chunk (identical conversion -> bitwise-identical scores)
      const int key = tid >> 2, seg = tid & 3;
      const float4* src = (const float4*)(kb_ + (size_t)(key0 + key) * DIM) + seg * 4;
      float4 a0 = src[0], a1 = src[1], a2 = src[2], a3 = src[3];
      f16x8 h0;
      h0[0]=(_Float16)a0.x; h0[1]=(_Float16)a0.y; h0[2]=(_Float16)a0.z; h0[3]=(_Float16)a0.w;
      h0[4]=(_Float16)a1.x; h0[5]=(_Float16)a1.y; h0[6]=(_Float16)a1.z; h0[7]=(_Float16)a1.w;
      *(f16x8*)(kc + kc_off(key, seg * 2)) = h0;
      f16x8 h1;
      h1[0]=(_Float16)a2.x; h1[1]=(_Float16)a2.y; h1[2]=(_Float16)a2.z; h1[3]=(_Float16)a2.w;
      h1[4]=(_Float16)a3.x; h1[5]=(_Float16)a3.y; h1[6]=(_Float16)a3.z; h1[7]=(_Float16)a3.w;
      *(f16x8*)(kc + kc_off(key, seg * 2 + 1)) = h1;
    }
    {  // stage V chunk transposed -> fp16 LDS
      const int key = tid >> 2, seg = tid & 3;
      const float4* src = (const float4*)(vb + (size_t)(key0 + key) * DIM) + seg * 4;
      float4 a0 = src[0], a1 = src[1], a2 = src[2], a3 = src[3];
      const int kbg = key >> 3, kl = key & 7;
      const int d0 = seg * 16;
      vt[vt_off(d0 +  0, kbg) + kl] = (_Float16)a0.x;
      vt[vt_off(d0 +  1, kbg) + kl] = (_Float16)a0.y;
      vt[vt_off(d0 +  2, kbg) + kl] = (_Float16)a0.z;
      vt[vt_off(d0 +  3, kbg) + kl] = (_Float16)a0.w;
      vt[vt_off(d0 +  4, kbg) + kl] = (_Float16)a1.x;
      vt[vt_off(d0 +  5, kbg) + kl] = (_Float16)a1.y;
      vt[vt_off(d0 +  6, kbg) + kl] = (_Float16)a1.z;
      vt[vt_off(d0 +  7, kbg) + kl] = (_Float16)a1.w;
      vt[vt_off(d0 +  8, kbg) + kl] = (_Float16)a2.x;
      vt[vt_off(d0 +  9, kbg) + kl] = (_Float16)a2.y;
      vt[vt_off(d0 + 10, kbg) + kl] = (_Float16)a2.z;
      vt[vt_off(d0 + 11, kbg) + kl] = (_Float16)a2.w;
      vt[vt_off(d0 + 12, kbg) + kl] = (_Float16)a3.x;
      vt[vt_off(d0 + 13, kbg) + kl] = (_Float16)a3.y;
      vt[vt_off(d0 + 14, kbg) + kl] = (_Float16)a3.z;
      vt[vt_off(d0 + 15, kbg) + kl] = (_Float16)a3.w;
    }
    __syncthreads();

#pragma unroll
    for (int grp = 0; grp < 2; ++grp) {
      // zero my P tile (each lane zeroes exactly its A-frag granule)
      *(f16x8*)(Pw + pb_off(am, aq)) = (f16x8){(_Float16)0,(_Float16)0,(_Float16)0,(_Float16)0,
                                               (_Float16)0,(_Float16)0,(_Float16)0,(_Float16)0};
#pragma unroll
      for (int t2 = 0; t2 < 2; ++t2) {
        const int keyloc = hh * 64 + grp * 32 + t2 * 16 + am;
        f16x8 b0 = *(const f16x8*)(kc + kc_off(keyloc, aq));
        f16x8 b1 = *(const f16x8*)(kc + kc_off(keyloc, aq + 4));
        f32x4 acc = {0.f, 0.f, 0.f, 0.f};
        acc = __builtin_amdgcn_mfma_f32_16x16x32_f16(A0, b0, acc, 0, 0, 0);
        acc = __builtin_amdgcn_mfma_f32_16x16x32_f16(A1, b1, acc, 0, 0, 0);
#pragma unroll
        for (int r = 0; r < 4; ++r) {
          float s = acc[r];
          if (s > thU_r[r]) {
            _Float16 wh = (_Float16)__expf(s - m_r[r]);
            zs[r] += (float)wh;          // z matches the fp16 weight used in PV
            c1l[r] += 1;
            const int m = aq * 4 + r, kl = t2 * 16 + am;
            Pw[m * 32 + (((kl >> 3) ^ (m & 3)) << 3) + (kl & 7)] = wh;
          } else if (s >= thU_r[r] - TH_GAP) {
            int rb = mt * 16 + aq * 4 + r;
            unsigned int p = atomicAdd(candCnt + rb, 1u);
            if (p < CCAP) candJ[rb * CCAP + p] = (unsigned short)(key0 + keyloc);
          }
        }
      }
      // PV mfma: out[16 m][64 d] += P[16 m][32 key] x V[32 key][64 d]
      f16x8 pA = *(const f16x8*)(Pw + pb_off(am, aq));
#pragma unroll
      for (int dt = 0; dt < 4; ++dt) {
        f16x8 vB = *(const f16x8*)(vt + vt_off(dt * 16 + am, hh * 8 + grp * 4 + aq));
        pv[dt] = __builtin_amdgcn_mfma_f32_16x16x32_f16(pA, vB, pv[dt], 0, 0, 0);
      }
    }
    __syncthreads();
  }

  // ---- dump PV accumulators + Z/C1 reductions ----
  for (int i = tid; i < MROWS * DIM; i += THREADS) outacc[i] = 0.f;
  __syncthreads();
#pragma unroll
  for (int dt = 0; dt < 4; ++dt)
#pragma unroll
    for (int r = 0; r < 4; ++r)
      atomicAdd(outacc + (mt * 16 + aq * 4 + r) * 64 + dt * 16 + am, pv[dt][r]);
#pragma unroll
  for (int off = 1; off < 16; off <<= 1)
#pragma unroll
    for (int r = 0; r < 4; ++r) {
      zs[r] += __shfl_xor(zs[r], off);
      c1l[r] += __shfl_xor(c1l[r], off);
    }
  if (am == 0) {
#pragma unroll
    for (int r = 0; r < 4; ++r) {
      int rb = mt * 16 + aq * 4 + r;
      atomicAdd(zrow + rb, zs[r]);
      atomicAdd(c1cnt + rb, (unsigned int)c1l[r]);
    }
  }
  __syncthreads();

  // ---- candidate resolution (R4 rewrite: 8x8 lane-parallel, no serial
  // dependent-load chains). cg = lane>>3 -> candidate slot, le = lane&7 ->
  // 8-element dim group. Dots: ceil(nc/8) rounds of [2 float4 loads, 8 FMA,
  // 3 shfl] vs 22 serial [load -> 6-shfl chain] before. ----
  unsigned short* wscr = (unsigned short*)(pbuf + wave * 512);  // per-wave scratch (PBUF dead)
  const int cg = lane >> 3, le = lane & 7;
  for (int i = 0; i < 8; ++i) {
    const int rb = wave * 8 + i;
    const int nc = min((int)candCnt[rb], CCAP);
    int need = KKEEP - (int)c1cnt[rb];
    need = need < 0 ? 0 : (need > nc ? nc : need);   // DEFENSIVE: never exceed nc
    const float mv = mval[rb];
    // q-row fragment for my 8 dims (shared across all candidate rounds)
    const float* qrow = qb + (size_t)(mrow0 + rb) * DIM + le * 8;
    float4 q0 = *(const float4*)qrow, q1 = *(const float4*)(qrow + 4);
    // exact fp32 dots, 8 candidates in parallel
    for (int base = 0; base < nc; base += 8) {
      const int c = base + cg;
      const bool act = c < nc;
      float p = 0.f;
      if (act) {
        int col = candJ[rb * CCAP + c] & (NK - 1);
        const float* kr = kb_ + (size_t)col * DIM + le * 8;
        float4 k0 = *(const float4*)kr, k1 = *(const float4*)(kr + 4);
        p = q0.x*k0.x + q0.y*k0.y + q0.z*k0.z + q0.w*k0.w
          + q1.x*k1.x + q1.y*k1.y + q1.z*k1.z + q1.w*k1.w;
        p *= QSCALE;
      }
      p += __shfl_xor(p, 1); p += __shfl_xor(p, 2); p += __shfl_xor(p, 4);
      if (act && le == 0) candS[rb * CCAP + c] = p;
    }
    // exact top-need threshold over candidate scores (radix on ordered bits)
    float sc = (lane < nc) ? candS[rb * CCAP + lane] : -1e30f;
    int bi = __float_as_int(sc);
    unsigned int u = (bi >= 0) ? ((unsigned int)bi | 0x80000000u) : ~(unsigned int)bi;
    unsigned int T = 0;
    for (int bit = 31; bit >= 0; --bit) {
      unsigned int trial = T | (1u << bit);
      unsigned long long mk = __ballot((lane < nc) && (u >= trial));
      if (__popcll(mk) >= need) T = trial;
    }
    bool sel = (lane < nc) && (u > T);
    int need2 = need - __popcll(__ballot(sel));
    int col_l = (lane < nc) ? (int)(candJ[rb * CCAP + lane] & (NK - 1)) : 0x7fffffff;
    int guard = 0;
    while (need2 > 0 && guard < CCAP) {  // np tie-break: lowest index first
      int cnd = (lane < nc && u == T && !sel) ? col_l : 0x7fffffff;
#pragma unroll
      for (int off = 1; off < 64; off <<= 1) cnd = min(cnd, __shfl_xor(cnd, off));
      if (lane < nc && u == T && col_l == cnd) sel = true;
      --need2; ++guard;
    }
    // compact selected candidate indices into per-wave scratch
    unsigned long long selm = __ballot(sel);
    const int scount = __popcll(selm);
    if (sel) {
      int slot = __popcll(selm & ((1ull << lane) - 1));
      wscr[slot] = (unsigned short)lane;
    }
    // 8x8-parallel weighted-V accumulation: cg -> selected slot, le -> dims
    float po0 = 0.f, po1 = 0.f, po2 = 0.f, po3 = 0.f;
    float po4 = 0.f, po5 = 0.f, po6 = 0.f, po7 = 0.f;
    float zp = 0.f;
    for (int base = 0; base < scount; base += 8) {
      const int slot = base + cg;
      if (slot < scount) {
        const int c = wscr[slot];
        const float w = __expf(candS[rb * CCAP + c] - mv);
        const int col = candJ[rb * CCAP + c] & (NK - 1);
        const float* vr = vb + (size_t)col * DIM + le * 8;
        float4 v0 = *(const float4*)vr, v1 = *(const float4*)(vr + 4);
        po0 += w * v0.x; po1 += w * v0.y; po2 += w * v0.z; po3 += w * v0.w;
        po4 += w * v1.x; po5 += w * v1.y; po6 += w * v1.z; po7 += w * v1.w;
        zp += w;   // same w across all 8 le lanes of this cg; reduced over cg only
      }
    }
#pragma unroll
    for (int off = 8; off < 64; off <<= 1) {
      po0 += __shfl_xor(po0, off); po1 += __shfl_xor(po1, off);
      po2 += __shfl_xor(po2, off); po3 += __shfl_xor(po3, off);
      po4 += __shfl_xor(po4, off); po5 += __shfl_xor(po5, off);
      po6 += __shfl_xor(po6, off); po7 += __shfl_xor(po7, off);
      zp  += __shfl_xor(zp,  off);
    }
    if (cg == 0) {   // lanes 0..7: le = lane; each writes its 8 dims
      float* orow = outacc + rb * 64 + le * 8;
      orow[0] += po0; orow[1] += po1; orow[2] += po2; orow[3] += po3;
      orow[4] += po4; orow[5] += po5; orow[6] += po6; orow[7] += po7;
      if (le == 0) zrow[rb] += zp;
    }
  }
  __syncthreads();

  // ---- normalize + write ----
  for (int i = tid; i < MROWS * DIM; i += THREADS) {
    int rb = i >> 6;
    ob[(size_t)(mrow0 + rb) * DIM + (i & 63)] = outacc[i] / zrow[rb];
  }
}

// ---------------------------------------------------------------------------
extern "C" void kernel_launch(void* const* d_in, const int* in_sizes, int n_in,
                              void* d_out, int out_size, void* d_ws,
                              size_t ws_size, hipStream_t stream) {
  const float* q = (const float*)d_in[0];
  const float* k = (const float*)d_in[1];
  const float* v = (const float*)d_in[2];
  float* out = (float*)d_out;
  const int nblocks = (BH_N * NK) / MROWS;  // 2048
  fused_topk_attn<<<nblocks, THREADS, 0, stream>>>(q, k, v, out);
}

// Round 5
// 985.803 us; speedup vs baseline: 2.3640x; 1.1870x over previous
//
#include <hip/hip_runtime.h>
#include <cstdint>
#include <cstddef>

#define BH_N    32
#define NK      4096
#define DIM     64
#define KKEEP   409
#define QSCALE  0.125f

#define MROWS   64
#define THREADS 512
#define CHUNK   128
#define NCHUNK  (NK / CHUNK)
// Histogram over [0.6, 2.6], 192 bins of width 1/96. Per-row threshold
// (409th of 4096) ~= 1.27*|q|/8; falling below 0.6 needs |q|<4.3,
// P(chi2_64 < 18.6) ~ 7e-9 per row -> safe.
#define HIST_LO 0.60f
#define HIST_INV 96.0f
#define HIST_BINS 192
#define EPS     0.005f
#define TH_GAP  (1.0f / HIST_INV + 4.0f * EPS)
#define CCAP    64

typedef _Float16 f16x8 __attribute__((ext_vector_type(8)));
typedef float f32x4 __attribute__((ext_vector_type(4)));

// ---- LDS layout (bytes). Regions reused across phases. ----
// Footprint 50944 B. Occupancy history: (512,4) is FINAL - forcing 6
// waves/EU spills (R1/R3: FETCH 62MB->2.4-2.7GB, dur +1000us). 2 blk/CU.
// R4: tail 8x8-parallelization 1475->1170us (theory matched).
// R5: staging was ~45% of VALU and on the barrier-critical path, with K
// converted twice and V transpose-scattered twice per bh. Prep kernel now
// materializes the EXACT swizzled LDS images once per (bh,chunk) in d_ws;
// main staging = linear global_load_lds copy (no cvt, no ds_write).
#define OFF_KC    0        // 16384 : fp16 K chunk [128 key][64 d], swizzled; reused as candS f32[64][64]
#define OFF_VT    16384    // 16384 : fp16 V chunk transposed [64 d][128 key], swizzled; reused as outacc f32[64][64]; Phase A: hist lo
#define OFF_PBUF  32768    // 8192  : per-wave P tile fp16 [16 m][32 k] (1024 B/wave) [Phase B]; Phase A: hist hi; tail: per-wave scratch
#define OFF_HIST  16384    // 24576 : u32 (u16-pair) hist [64 row][96]  (= VT+PBUF regions, Phase A only)
#define OFF_CANDJ 40960    // 8192  : u16 [64 row][64] [Phase B + resolution]
#define OFF_MISC  49152    // rmaxI i32[64], thU f32[64], (gap), mval f32[64], candCnt u32[64], c1cnt u32[64], zrow f32[64]
#define SMEM_SZ   (49152 + 7*256)

#define IMG_HALFS (CHUNK * DIM)            // 8192 halfs = 16384 B per chunk image
#define WS_NEED   ((size_t)2 * BH_N * NCHUNK * IMG_HALFS * sizeof(_Float16))  // 32 MB

__device__ __forceinline__ int kc_off(int key, int g) {   // halfs; granule g = d/8
  return key * 64 + ((g ^ (key & 7)) << 3);
}
// V-transpose swizzle folds in BOTH d&15 and d>>4 (R1: staging write
// conflicts 9.75e7 -> 4.7e7).
__device__ __forceinline__ int vt_off(int d, int kb) {    // halfs; granule kb = key/8
  return d * 128 + ((kb ^ (d & 15) ^ (d >> 4)) << 3);
}
__device__ __forceinline__ int pb_off(int m, int g) {     // halfs; granule g = k/8
  return m * 32 + ((g ^ (m & 3)) << 3);
}

// global -> LDS direct copy, 16 B per lane. LDS dest is wave-uniform base
// + lane*16 (HW rule); global src is per-lane. Images are pre-swizzled so
// the copy is linear on both sides.
typedef const __attribute__((address_space(1))) unsigned int gu32_t;
typedef __attribute__((address_space(3))) unsigned int lu32_t;
__device__ __forceinline__ void gload_lds16(const void* g, void* l) {
  __builtin_amdgcn_global_load_lds((gu32_t*)g, (lu32_t*)l, 16, 0, 0);
}

// ===================== prep: materialize swizzled LDS images =====================
// One block per (bh, chunk). kimg[key,g] and vimg[d,kb] hold the EXACT byte
// image the main kernel previously built in LDS, with bitwise-identical
// f32->f16 conversion (scores unchanged; absmax must stay 0.005859375).
__global__ __launch_bounds__(512) void prep_images(
    const float* __restrict__ k, const float* __restrict__ v,
    _Float16* __restrict__ kimg, _Float16* __restrict__ vimg) {
  __shared__ float vstage[CHUNK * DIM];  // 32 KB
  const int bid = blockIdx.x;            // bh * NCHUNK + ch (contiguous tiling)
  const int t = threadIdx.x;
  const float* kb_ = k + (size_t)bid * CHUNK * DIM;
  const float* vb  = v + (size_t)bid * CHUNK * DIM;
  _Float16* ki = kimg + (size_t)bid * IMG_HALFS;
  _Float16* vi = vimg + (size_t)bid * IMG_HALFS;
  // stage V chunk into LDS (coalesced float4), K needs no staging
#pragma unroll
  for (int s = 0; s < 4; ++s)
    ((float4*)vstage)[t + s * 512] = ((const float4*)vb)[t + s * 512];
  // K image: slot (key, g) -> 8 contiguous f32 -> f16x8 at kc_off
#pragma unroll
  for (int s = 0; s < 2; ++s) {
    const int sid = t + s * 512, key = sid >> 3, g = sid & 7;
    const float* kr = kb_ + key * DIM + g * 8;
    float4 a0 = *(const float4*)kr, a1 = *(const float4*)(kr + 4);
    f16x8 h;
    h[0]=(_Float16)a0.x; h[1]=(_Float16)a0.y; h[2]=(_Float16)a0.z; h[3]=(_Float16)a0.w;
    h[4]=(_Float16)a1.x; h[5]=(_Float16)a1.y; h[6]=(_Float16)a1.z; h[7]=(_Float16)a1.w;
    *(f16x8*)(ki + kc_off(key, g)) = h;
  }
  __syncthreads();
  // V image: transpose from LDS, slot (d, kb) covers keys kb*8..kb*8+7
#pragma unroll
  for (int s = 0; s < 2; ++s) {
    const int sid = t + s * 512, d = sid >> 4, kb = sid & 15;
    f16x8 h;
#pragma unroll
    for (int j = 0; j < 8; ++j) h[j] = (_Float16)vstage[(kb * 8 + j) * DIM + d];
    *(f16x8*)(vi + vt_off(d, kb)) = h;
  }
}

// ===================== main kernel =====================
template <bool PRE>
__global__ __launch_bounds__(THREADS, 4) void fused_topk_attn(
    const float* __restrict__ q, const float* __restrict__ k,
    const float* __restrict__ v, float* __restrict__ out,
    const _Float16* __restrict__ kimg, const _Float16* __restrict__ vimg) {
  __shared__ __align__(16) unsigned char smem[SMEM_SZ];
  _Float16* kc   = (_Float16*)(smem + OFF_KC);
  _Float16* vt   = (_Float16*)(smem + OFF_VT);
  unsigned int* hist = (unsigned int*)(smem + OFF_HIST);
  _Float16* pbuf = (_Float16*)(smem + OFF_PBUF);
  unsigned short* candJ = (unsigned short*)(smem + OFF_CANDJ);
  int*   rmaxI  = (int*)(smem + OFF_MISC);
  float* thU    = (float*)(smem + OFF_MISC + 256);
  float* mval   = (float*)(smem + OFF_MISC + 768);
  unsigned int* candCnt = (unsigned int*)(smem + OFF_MISC + 1024);
  unsigned int* c1cnt   = (unsigned int*)(smem + OFF_MISC + 1280);
  float* zrow   = (float*)(smem + OFF_MISC + 1536);
  float* candS  = (float*)(smem + OFF_KC);     // reuse Kc after chunks
  float* outacc = (float*)(smem + OFF_VT);     // reuse Vt after chunks

  const int tid  = threadIdx.x;
  const int wave = tid >> 6, lane = tid & 63;
  const int am = lane & 15, aq = lane >> 4;    // mfma lane coords
  const int mt = wave & 3, hh = wave >> 2;     // m-tile, n-half

  // Grid mapping: same-bh blocks land on the same XCD (L2 locality).
  const int bid = blockIdx.x;
  const int xcd = bid & 7, idx = bid >> 3;
  const int bh  = xcd + 8 * (idx >> 6);
  const int mrow0 = (idx & 63) * MROWS;

  const float* qb = q + (size_t)bh * NK * DIM;
  const float* kb_ = k + (size_t)bh * NK * DIM;
  const float* vb = v + (size_t)bh * NK * DIM;
  float* ob = out + (size_t)bh * NK * DIM;

  // ---- init LDS ----
  for (int i = tid; i < 64 * (HIST_BINS / 2); i += THREADS) hist[i] = 0u;
  if (tid < 64) rmaxI[tid] = 0;
  __syncthreads();

  // ---- A-fragments (q/8 in fp16), persist in registers ----
  const int rbase = mrow0 + mt * 16;
  f16x8 A0, A1;
  {
    const float* qrow = qb + (size_t)(rbase + am) * DIM + aq * 8;
#pragma unroll
    for (int j = 0; j < 8; ++j) A0[j] = (_Float16)(qrow[j] * QSCALE);
#pragma unroll
    for (int j = 0; j < 8; ++j) A1[j] = (_Float16)(qrow[32 + j] * QSCALE);
  }

  // ================= PHASE A: screen GEMM -> max + histogram =================
  float rmax[4] = {-1e30f, -1e30f, -1e30f, -1e30f};
#pragma unroll 1
  for (int ch = 0; ch < NCHUNK; ++ch) {
    const int key0 = ch * CHUNK;
    if constexpr (PRE) {  // linear copy of the pre-swizzled 16 KB K image
      const char* src = (const char*)(kimg + (size_t)(bh * NCHUNK + ch) * IMG_HALFS);
#pragma unroll
      for (int r = 0; r < 2; ++r)
        gload_lds16(src + r * 8192 + wave * 1024 + lane * 16,
                    smem + OFF_KC + r * 8192 + wave * 1024);
    } else {  // fallback: stage K chunk -> fp16 LDS in-kernel
      const int key = tid >> 2, seg = tid & 3;
      const float4* src = (const float4*)(kb_ + (size_t)(key0 + key) * DIM) + seg * 4;
      float4 a0 = src[0], a1 = src[1], a2 = src[2], a3 = src[3];
      f16x8 h0;
      h0[0]=(_Float16)a0.x; h0[1]=(_Float16)a0.y; h0[2]=(_Float16)a0.z; h0[3]=(_Float16)a0.w;
      h0[4]=(_Float16)a1.x; h0[5]=(_Float16)a1.y; h0[6]=(_Float16)a1.z; h0[7]=(_Float16)a1.w;
      *(f16x8*)(kc + kc_off(key, seg * 2)) = h0;
      f16x8 h1;
      h1[0]=(_Float16)a2.x; h1[1]=(_Float16)a2.y; h1[2]=(_Float16)a2.z; h1[3]=(_Float16)a2.w;
      h1[4]=(_Float16)a3.x; h1[5]=(_Float16)a3.y; h1[6]=(_Float16)a3.z; h1[7]=(_Float16)a3.w;
      *(f16x8*)(kc + kc_off(key, seg * 2 + 1)) = h1;
    }
    __syncthreads();
#pragma unroll
    for (int tl = 0; tl < 4; ++tl) {
      const int keyloc = hh * 64 + tl * 16 + am;
      f16x8 b0 = *(const f16x8*)(kc + kc_off(keyloc, aq));
      f16x8 b1 = *(const f16x8*)(kc + kc_off(keyloc, aq + 4));
      f32x4 acc = {0.f, 0.f, 0.f, 0.f};
      acc = __builtin_amdgcn_mfma_f32_16x16x32_f16(A0, b0, acc, 0, 0, 0);
      acc = __builtin_amdgcn_mfma_f32_16x16x32_f16(A1, b1, acc, 0, 0, 0);
#pragma unroll
      for (int r = 0; r < 4; ++r) {
        float s = acc[r];
        rmax[r] = fmaxf(rmax[r], s);
        if (s >= HIST_LO) {
          int bin = (int)((s - HIST_LO) * HIST_INV);
          bin = bin > (HIST_BINS - 1) ? (HIST_BINS - 1) : bin;
          atomicAdd(hist + (mt * 16 + aq * 4 + r) * (HIST_BINS / 2) + (bin >> 1),
                    (bin & 1) ? 65536u : 1u);
        }
      }
    }
    __syncthreads();
  }
  // row max -> LDS
#pragma unroll
  for (int off = 1; off < 16; off <<= 1)
#pragma unroll
    for (int r = 0; r < 4; ++r) rmax[r] = fmaxf(rmax[r], __shfl_xor(rmax[r], off));
  if (am == 0) {
#pragma unroll
    for (int r = 0; r < 4; ++r)
      atomicMax(rmaxI + mt * 16 + aq * 4 + r, __float_as_int(rmax[r]));
  }
  __syncthreads();

  // ---- per-row threshold bracket from histogram ----
  if (tid < 64) {
    const unsigned int* hrow = hist + tid * (HIST_BINS / 2);
    unsigned int cum = 0; int bsel = 0;
    for (int b = HIST_BINS - 1; b >= 0; --b) {
      unsigned int pr = hrow[b >> 1];
      cum += (b & 1) ? (pr >> 16) : (pr & 0xffffu);
      if (cum >= KKEEP) { bsel = b; break; }
    }
    float lowerE = HIST_LO + (float)bsel * (1.0f / HIST_INV);
    float upperE = lowerE + (1.0f / HIST_INV);
    thU[tid] = upperE + 2.0f * EPS;
    mval[tid] = __int_as_float(rmaxI[tid]);
    candCnt[tid] = 0u; c1cnt[tid] = 0u; zrow[tid] = 0.f;
  }
  __syncthreads();

  float thU_r[4], m_r[4];
#pragma unroll
  for (int r = 0; r < 4; ++r) {
    int rb = mt * 16 + aq * 4 + r;
    thU_r[r] = thU[rb]; m_r[r] = mval[rb];
  }

  // ================= PHASE B: re-screen + classify + fused PV-MFMA =================
  f32x4 pv[4];
#pragma unroll
  for (int d = 0; d < 4; ++d) pv[d] = (f32x4){0.f, 0.f, 0.f, 0.f};
  float zs[4] = {0.f, 0.f, 0.f, 0.f};
  int c1l[4] = {0, 0, 0, 0};
  _Float16* Pw = pbuf + wave * 512;

#pragma unroll 1
  for (int ch = 0; ch < NCHUNK; ++ch) {
    const int key0 = ch * CHUNK;
    if constexpr (PRE) {  // linear copies of pre-swizzled K and V images
      const char* ksrc = (const char*)(kimg + (size_t)(bh * NCHUNK + ch) * IMG_HALFS);
      const char* vsrc = (const char*)(vimg + (size_t)(bh * NCHUNK + ch) * IMG_HALFS);
#pragma unroll
      for (int r = 0; r < 2; ++r) {
        gload_lds16(ksrc + r * 8192 + wave * 1024 + lane * 16,
                    smem + OFF_KC + r * 8192 + wave * 1024);
        gload_lds16(vsrc + r * 8192 + wave * 1024 + lane * 16,
                    smem + OFF_VT + r * 8192 + wave * 1024);
      }
    } else {
      {  // stage K chunk (identical conversion -> bitwise-identical scores)
        const int key = tid >> 2, seg = tid & 3;
        const float4* src = (const float4*)(kb_ + (size_t)(key0 + key) * DIM) + seg * 4;
        float4 a0 = src[0], a1 = src[1], a2 = src[2], a3 = src[3];
        f16x8 h0;
        h0[0]=(_Float16)a0.x; h0[1]=(_Float16)a0.y; h0[2]=(_Float16)a0.z; h0[3]=(_Float16)a0.w;
        h0[4]=(_Float16)a1.x; h0[5]=(_Float16)a1.y; h0[6]=(_Float16)a1.z; h0[7]=(_Float16)a1.w;
        *(f16x8*)(kc + kc_off(key, seg * 2)) = h0;
        f16x8 h1;
        h1[0]=(_Float16)a2.x; h1[1]=(_Float16)a2.y; h1[2]=(_Float16)a2.z; h1[3]=(_Float16)a2.w;
        h1[4]=(_Float16)a3.x; h1[5]=(_Float16)a3.y; h1[6]=(_Float16)a3.z; h1[7]=(_Float16)a3.w;
        *(f16x8*)(kc + kc_off(key, seg * 2 + 1)) = h1;
      }
      {  // stage V chunk transposed -> fp16 LDS
        const int key = tid >> 2, seg = tid & 3;
        const float4* src = (const float4*)(vb + (size_t)(key0 + key) * DIM) + seg * 4;
        float4 a0 = src[0], a1 = src[1], a2 = src[2], a3 = src[3];
        const int kbg = key >> 3, kl = key & 7;
        const int d0 = seg * 16;
        vt[vt_off(d0 +  0, kbg) + kl] = (_Float16)a0.x;
        vt[vt_off(d0 +  1, kbg) + kl] = (_Float16)a0.y;
        vt[vt_off(d0 +  2, kbg) + kl] = (_Float16)a0.z;
        vt[vt_off(d0 +  3, kbg) + kl] = (_Float16)a0.w;
        vt[vt_off(d0 +  4, kbg) + kl] = (_Float16)a1.x;
        vt[vt_off(d0 +  5, kbg) + kl] = (_Float16)a1.y;
        vt[vt_off(d0 +  6, kbg) + kl] = (_Float16)a1.z;
        vt[vt_off(d0 +  7, kbg) + kl] = (_Float16)a1.w;
        vt[vt_off(d0 +  8, kbg) + kl] = (_Float16)a2.x;
        vt[vt_off(d0 +  9, kbg) + kl] = (_Float16)a2.y;
        vt[vt_off(d0 + 10, kbg) + kl] = (_Float16)a2.z;
        vt[vt_off(d0 + 11, kbg) + kl] = (_Float16)a2.w;
        vt[vt_off(d0 + 12, kbg) + kl] = (_Float16)a3.x;
        vt[vt_off(d0 + 13, kbg) + kl] = (_Float16)a3.y;
        vt[vt_off(d0 + 14, kbg) + kl] = (_Float16)a3.z;
        vt[vt_off(d0 + 15, kbg) + kl] = (_Float16)a3.w;
      }
    }
    __syncthreads();

#pragma unroll
    for (int grp = 0; grp < 2; ++grp) {
      // zero my P tile (each lane zeroes exactly its A-frag granule)
      *(f16x8*)(Pw + pb_off(am, aq)) = (f16x8){(_Float16)0,(_Float16)0,(_Float16)0,(_Float16)0,
                                               (_Float16)0,(_Float16)0,(_Float16)0,(_Float16)0};
#pragma unroll
      for (int t2 = 0; t2 < 2; ++t2) {
        const int keyloc = hh * 64 + grp * 32 + t2 * 16 + am;
        f16x8 b0 = *(const f16x8*)(kc + kc_off(keyloc, aq));
        f16x8 b1 = *(const f16x8*)(kc + kc_off(keyloc, aq + 4));
        f32x4 acc = {0.f, 0.f, 0.f, 0.f};
        acc = __builtin_amdgcn_mfma_f32_16x16x32_f16(A0, b0, acc, 0, 0, 0);
        acc = __builtin_amdgcn_mfma_f32_16x16x32_f16(A1, b1, acc, 0, 0, 0);
#pragma unroll
        for (int r = 0; r < 4; ++r) {
          float s = acc[r];
          if (s > thU_r[r]) {
            _Float16 wh = (_Float16)__expf(s - m_r[r]);
            zs[r] += (float)wh;          // z matches the fp16 weight used in PV
            c1l[r] += 1;
            const int m = aq * 4 + r, kl = t2 * 16 + am;
            Pw[m * 32 + (((kl >> 3) ^ (m & 3)) << 3) + (kl & 7)] = wh;
          } else if (s >= thU_r[r] - TH_GAP) {
            int rb = mt * 16 + aq * 4 + r;
            unsigned int p = atomicAdd(candCnt + rb, 1u);
            if (p < CCAP) candJ[rb * CCAP + p] = (unsigned short)(key0 + keyloc);
          }
        }
      }
      // PV mfma: out[16 m][64 d] += P[16 m][32 key] x V[32 key][64 d]
      f16x8 pA = *(const f16x8*)(Pw + pb_off(am, aq));
#pragma unroll
      for (int dt = 0; dt < 4; ++dt) {
        f16x8 vB = *(const f16x8*)(vt + vt_off(dt * 16 + am, hh * 8 + grp * 4 + aq));
        pv[dt] = __builtin_amdgcn_mfma_f32_16x16x32_f16(pA, vB, pv[dt], 0, 0, 0);
      }
    }
    __syncthreads();
  }

  // ---- dump PV accumulators + Z/C1 reductions ----
  for (int i = tid; i < MROWS * DIM; i += THREADS) outacc[i] = 0.f;
  __syncthreads();
#pragma unroll
  for (int dt = 0; dt < 4; ++dt)
#pragma unroll
    for (int r = 0; r < 4; ++r)
      atomicAdd(outacc + (mt * 16 + aq * 4 + r) * 64 + dt * 16 + am, pv[dt][r]);
#pragma unroll
  for (int off = 1; off < 16; off <<= 1)
#pragma unroll
    for (int r = 0; r < 4; ++r) {
      zs[r] += __shfl_xor(zs[r], off);
      c1l[r] += __shfl_xor(c1l[r], off);
    }
  if (am == 0) {
#pragma unroll
    for (int r = 0; r < 4; ++r) {
      int rb = mt * 16 + aq * 4 + r;
      atomicAdd(zrow + rb, zs[r]);
      atomicAdd(c1cnt + rb, (unsigned int)c1l[r]);
    }
  }
  __syncthreads();

  // ---- candidate resolution (8x8 lane-parallel; R4, verified -21%) ----
  unsigned short* wscr = (unsigned short*)(pbuf + wave * 512);  // per-wave scratch (PBUF dead)
  const int cg = lane >> 3, le = lane & 7;
  for (int i = 0; i < 8; ++i) {
    const int rb = wave * 8 + i;
    const int nc = min((int)candCnt[rb], CCAP);
    int need = KKEEP - (int)c1cnt[rb];
    need = need < 0 ? 0 : (need > nc ? nc : need);   // DEFENSIVE: never exceed nc
    const float mv = mval[rb];
    // q-row fragment for my 8 dims (shared across all candidate rounds)
    const float* qrow = qb + (size_t)(mrow0 + rb) * DIM + le * 8;
    float4 q0 = *(const float4*)qrow, q1 = *(const float4*)(qrow + 4);
    // exact fp32 dots, 8 candidates in parallel
    for (int base = 0; base < nc; base += 8) {
      const int c = base + cg;
      const bool act = c < nc;
      float p = 0.f;
      if (act) {
        int col = candJ[rb * CCAP + c] & (NK - 1);
        const float* kr = kb_ + (size_t)col * DIM + le * 8;
        float4 k0 = *(const float4*)kr, k1 = *(const float4*)(kr + 4);
        p = q0.x*k0.x + q0.y*k0.y + q0.z*k0.z + q0.w*k0.w
          + q1.x*k1.x + q1.y*k1.y + q1.z*k1.z + q1.w*k1.w;
        p *= QSCALE;
      }
      p += __shfl_xor(p, 1); p += __shfl_xor(p, 2); p += __shfl_xor(p, 4);
      if (act && le == 0) candS[rb * CCAP + c] = p;
    }
    // exact top-need threshold over candidate scores (radix on ordered bits)
    float sc = (lane < nc) ? candS[rb * CCAP + lane] : -1e30f;
    int bi = __float_as_int(sc);
    unsigned int u = (bi >= 0) ? ((unsigned int)bi | 0x80000000u) : ~(unsigned int)bi;
    unsigned int T = 0;
    for (int bit = 31; bit >= 0; --bit) {
      unsigned int trial = T | (1u << bit);
      unsigned long long mk = __ballot((lane < nc) && (u >= trial));
      if (__popcll(mk) >= need) T = trial;
    }
    bool sel = (lane < nc) && (u > T);
    int need2 = need - __popcll(__ballot(sel));
    int col_l = (lane < nc) ? (int)(candJ[rb * CCAP + lane] & (NK - 1)) : 0x7fffffff;
    int guard = 0;
    while (need2 > 0 && guard < CCAP) {  // np tie-break: lowest index first
      int cnd = (lane < nc && u == T && !sel) ? col_l : 0x7fffffff;
#pragma unroll
      for (int off = 1; off < 64; off <<= 1) cnd = min(cnd, __shfl_xor(cnd, off));
      if (lane < nc && u == T && col_l == cnd) sel = true;
      --need2; ++guard;
    }
    // compact selected candidate indices into per-wave scratch
    unsigned long long selm = __ballot(sel);
    const int scount = __popcll(selm);
    if (sel) {
      int slot = __popcll(selm & ((1ull << lane) - 1));
      wscr[slot] = (unsigned short)lane;
    }
    // 8x8-parallel weighted-V accumulation: cg -> selected slot, le -> dims
    float po0 = 0.f, po1 = 0.f, po2 = 0.f, po3 = 0.f;
    float po4 = 0.f, po5 = 0.f, po6 = 0.f, po7 = 0.f;
    float zp = 0.f;
    for (int base = 0; base < scount; base += 8) {
      const int slot = base + cg;
      if (slot < scount) {
        const int c = wscr[slot];
        const float w = __expf(candS[rb * CCAP + c] - mv);
        const int col = candJ[rb * CCAP + c] & (NK - 1);
        const float* vr = vb + (size_t)col * DIM + le * 8;
        float4 v0 = *(const float4*)vr, v1 = *(const float4*)(vr + 4);
        po0 += w * v0.x; po1 += w * v0.y; po2 += w * v0.z; po3 += w * v0.w;
        po4 += w * v1.x; po5 += w * v1.y; po6 += w * v1.z; po7 += w * v1.w;
        zp += w;   // same w across all 8 le lanes of this cg; reduced over cg only
      }
    }
#pragma unroll
    for (int off = 8; off < 64; off <<= 1) {
      po0 += __shfl_xor(po0, off); po1 += __shfl_xor(po1, off);
      po2 += __shfl_xor(po2, off); po3 += __shfl_xor(po3, off);
      po4 += __shfl_xor(po4, off); po5 += __shfl_xor(po5, off);
      po6 += __shfl_xor(po6, off); po7 += __shfl_xor(po7, off);
      zp  += __shfl_xor(zp,  off);
    }
    if (cg == 0) {   // lanes 0..7: le = lane; each writes its 8 dims
      float* orow = outacc + rb * 64 + le * 8;
      orow[0] += po0; orow[1] += po1; orow[2] += po2; orow[3] += po3;
      orow[4] += po4; orow[5] += po5; orow[6] += po6; orow[7] += po7;
      if (le == 0) zrow[rb] += zp;
    }
  }
  __syncthreads();

  // ---- normalize + write ----
  for (int i = tid; i < MROWS * DIM; i += THREADS) {
    int rb = i >> 6;
    ob[(size_t)(mrow0 + rb) * DIM + (i & 63)] = outacc[i] / zrow[rb];
  }
}

// ---------------------------------------------------------------------------
extern "C" void kernel_launch(void* const* d_in, const int* in_sizes, int n_in,
                              void* d_out, int out_size, void* d_ws,
                              size_t ws_size, hipStream_t stream) {
  const float* q = (const float*)d_in[0];
  const float* k = (const float*)d_in[1];
  const float* v = (const float*)d_in[2];
  float* out = (float*)d_out;
  const int nblocks = (BH_N * NK) / MROWS;  // 2048
  if (d_ws != nullptr && ws_size >= WS_NEED) {
    _Float16* kimg = (_Float16*)d_ws;
    _Float16* vimg = kimg + (size_t)BH_N * NCHUNK * IMG_HALFS;
    prep_images<<<BH_N * NCHUNK, 512, 0, stream>>>(k, v, kimg, vimg);
    fused_topk_attn<true><<<nblocks, THREADS, 0, stream>>>(q, k, v, out, kimg, vimg);
  } else {
    fused_topk_attn<false><<<nblocks, THREADS, 0, stream>>>(q, k, v, out, nullptr, nullptr);
  }
}